// Round 1
// baseline (448.356 us; speedup 1.0000x reference)
//
#include <hip/hip_runtime.h>

typedef __bf16 bf16x8 __attribute__((ext_vector_type(8)));
typedef float  f32x4  __attribute__((ext_vector_type(4)));

__device__ __forceinline__ float lrelu(float x, float s){ return x > 0.f ? x : s*x; }

// ---------------- prep: weights fp32 -> bf16 TRANSPOSED, S cast, flag detect, cursor zero ----------------
// W1T/W2T: [128][128] with WT[n][k] = W[k][n]; W3T: [64][128]; Sb: straight cast of S[512][64]
// (final GEMM needs BT[n][k] = ST[k][n] = S[n][k] -> Sb is already the transposed-B layout).
__global__ void prep_k(const float* __restrict__ W1, const float* __restrict__ W2,
                       const float* __restrict__ W3, const float* __restrict__ S,
                       const int* __restrict__ ei,
                       __bf16* __restrict__ W1T, __bf16* __restrict__ W2T,
                       __bf16* __restrict__ W3T, __bf16* __restrict__ Sb,
                       int* __restrict__ flag, int* __restrict__ cursor, int N){
  int t = blockIdx.x*256 + threadIdx.x;
  if (t < N) cursor[t] = 0;
  if (t == 0){
    int is64 = 1;
    for (int k=1; k<64; k+=2) if (ei[k] != 0){ is64 = 0; break; }
    *flag = is64;
  }
  if (t < 16384){ int k = t>>7, n = t&127; W1T[n*128 + k] = (__bf16)W1[t]; }
  else if (t < 32768){ int i = t-16384; int k = i>>7, n = i&127; W2T[n*128 + k] = (__bf16)W2[i]; }
  else if (t < 40960){ int i = t-32768; int k = i>>6, n = i&63;  W3T[n*128 + k] = (__bf16)W3[i]; }
  else if (t < 73728){ int i = t-40960; Sb[i] = (__bf16)S[i]; }
}

// ---------------- CSR build ----------------
__global__ void hist_k(const int* __restrict__ ei, const int* __restrict__ flag,
                       int E, int* __restrict__ cnt){
  int t = blockIdx.x*256 + threadIdx.x;
  if (t >= E) return;
  int f = *flag;
  long di = f ? 2L*((long)E + t) : (long)(E + t);
  atomicAdd(&cnt[ei[di]], 1);
}

__global__ void scan1_k(const int* __restrict__ cnt, int* __restrict__ off,
                        int* __restrict__ bsum, int n){
  __shared__ int sc[1024];
  int t = threadIdx.x;
  int i = blockIdx.x*1024 + t;
  int v = (i < n) ? cnt[i] : 0;
  sc[t] = v; __syncthreads();
  for (int d=1; d<1024; d<<=1){
    int x = (t >= d) ? sc[t-d] : 0;
    __syncthreads();
    sc[t] += x;
    __syncthreads();
  }
  if (i < n) off[i] = sc[t] - v;
  if (t == 1023) bsum[blockIdx.x] = sc[1023];
}

__global__ void scan3_k(int* __restrict__ off, const int* __restrict__ bsum,
                        int* __restrict__ cursor, int n, int E){
  __shared__ int base_s;
  if (threadIdx.x == 0){
    int run = 0;
    for (int b=0; b<(int)blockIdx.x; b++) run += bsum[b];
    base_s = run;
  }
  __syncthreads();
  int i = blockIdx.x*1024 + threadIdx.x;
  if (i < n){
    int v = off[i] + base_s;
    off[i] = v;
    cursor[i] = v;
  }
  if (i == 0) off[n] = E;
}

__global__ void scatter_k(const int* __restrict__ ei, const int* __restrict__ flag,
                          int E, int* __restrict__ cursor, int* __restrict__ csr){
  int t = blockIdx.x*256 + threadIdx.x;
  if (t >= E) return;
  int f = *flag;
  int s = ei[f ? 2L*(long)t         : (long)t];
  int d = ei[f ? 2L*((long)E + t)   : (long)(E + t)];
  int pos = atomicAdd(&cursor[d], 1);
  csr[pos] = s;
}

// ---------------- GEMM + fused alpha-dot epilogue ----------------
// C[M,Ntot] = A[M,K] @ B; B passed PRE-TRANSPOSED as BTg[Ntot][K] -> staging is a straight
// b128 copy (no per-element transpose, no int division).
// A frag: A[m=lane&15][k=(lane>>4)*8+j]; B frag: BT[n=lane&15][k]; C/D: col=lane&15, row=(lane>>4)*4+reg.
template<int K, bool AF32, bool ALPH, bool OUTBF>
__global__ __launch_bounds__(256) void gemm_k(const __bf16* __restrict__ A,
        const float* __restrict__ Af, const __bf16* __restrict__ BTg,
        float* __restrict__ Cf, __bf16* __restrict__ Cb,
        const float* __restrict__ avs, const float* __restrict__ avd,
        float* __restrict__ as_, float* __restrict__ ad_,
        int M, int Ntot){
  constexpr int KP = K + 8;                    // rows stay 16B-aligned, 2-way-max bank alias
  constexpr int KV = K / 8;                    // bf16x8 chunks per row
  __shared__ __align__(16) __bf16 BT[128*KP];  // BT[n][k]
  const int n0 = blockIdx.y * 128;
  const int BN = min(128, Ntot - n0);
  const int tid = threadIdx.x;
  for (int idx = tid; idx < BN*KV; idx += 256){
    int nn = idx / KV, k8 = idx - nn*KV;       // KV is power of 2 -> shifts
    *(bf16x8*)&BT[nn*KP + k8*8] = *(const bf16x8*)(BTg + (size_t)(n0+nn)*K + k8*8);
  }
  __syncthreads();
  const int lane = tid & 63, wave = tid >> 6;
  const int row0 = (blockIdx.x*4 + wave) * 16;
  if (row0 >= M) return;
  const int m = lane & 15, kq = lane >> 4;
  bf16x8 af[K/32];
  if (AF32){
    const float* Ap = Af + (size_t)(row0 + m)*K + kq*8;
    #pragma unroll
    for (int ks=0; ks<K/32; ks++){
      f32x4 lo = *(const f32x4*)(Ap + ks*32);
      f32x4 hi = *(const f32x4*)(Ap + ks*32 + 4);
      bf16x8 v;
      #pragma unroll
      for (int j=0; j<4; j++){ v[j] = (__bf16)lo[j]; v[4+j] = (__bf16)hi[j]; }
      af[ks] = v;
    }
  } else {
    const __bf16* Ap = A + (size_t)(row0 + m)*K + kq*8;
    #pragma unroll
    for (int ks=0; ks<K/32; ks++) af[ks] = *(const bf16x8*)(Ap + ks*32);
  }
  float ps[4] = {0,0,0,0}, pd[4] = {0,0,0,0};
  const int ntc = BN >> 4;
  for (int nt=0; nt<ntc; nt++){
    f32x4 acc = {0.f, 0.f, 0.f, 0.f};
    const __bf16* Bp = &BT[(nt*16 + m)*KP + kq*8];
    #pragma unroll
    for (int ks=0; ks<K/32; ks++){
      bf16x8 bf = *(const bf16x8*)(Bp + ks*32);
      acc = __builtin_amdgcn_mfma_f32_16x16x32_bf16(af[ks], bf, acc, 0, 0, 0);
    }
    if (ALPH){
      float vs = avs[n0 + nt*16 + m], vd = avd[n0 + nt*16 + m];
      #pragma unroll
      for (int r=0; r<4; r++){ ps[r] += acc[r]*vs; pd[r] += acc[r]*vd; }
    }
    size_t cb = (size_t)(row0 + kq*4)*Ntot + (n0 + nt*16 + m);
    #pragma unroll
    for (int r=0; r<4; r++){
      if (OUTBF) Cb[cb + (size_t)r*Ntot] = (__bf16)acc[r];
      else       Cf[cb + (size_t)r*Ntot] = acc[r];
    }
  }
  if (ALPH){
    #pragma unroll
    for (int o=1; o<16; o<<=1){
      #pragma unroll
      for (int r=0; r<4; r++){ ps[r] += __shfl_xor(ps[r], o); pd[r] += __shfl_xor(pd[r], o); }
    }
    if (m == 0){
      #pragma unroll
      for (int r=0; r<4; r++){
        as_[row0 + kq*4 + r] = ps[r];
        ad_[row0 + kq*4 + r] = pd[r];
      }
    }
  }
}

// ---------------- per-dst-node softmax aggregation: single-pass online softmax ----------------
// One wave per node (persistent, wave-strided). No LDS, no barriers:
// per-chunk max via shuffles + flash-style rescale; w/s broadcast via v_readlane (SGPR base
// for the h-row gather).
template<int F, int ACT>
__global__ __launch_bounds__(256) void aggregate_k(const __bf16* __restrict__ h,
        const float* __restrict__ as, const float* __restrict__ ad,
        const int* __restrict__ off, const int* __restrict__ csr,
        const float* __restrict__ bias, __bf16* __restrict__ y, int N){
  const int lane = threadIdx.x & 63;
  const int wid  = (blockIdx.x*256 + threadIdx.x) >> 6;
  const int nw   = gridDim.x * 4;
  for (int i = wid; i < N; i += nw){
    const int beg = off[i], end = off[i+1];
    const float adi = ad[i];
    const float e_self = lrelu(as[i] + adi, 0.2f);
    float m = e_self, dsum = 0.f, acc0 = 0.f, acc1 = 0.f;
    for (int base = beg; base < end; base += 64){
      const int p = base + lane;
      int s = 0; float e = -1e30f;
      if (p < end){ s = csr[p]; e = lrelu(as[s] + adi, 0.2f); }
      float cm = e;
      #pragma unroll
      for (int o=32; o; o>>=1) cm = fmaxf(cm, __shfl_xor(cm, o));
      if (cm > m){                       // wave-uniform branch
        const float sc = __expf(m - cm);
        acc0 *= sc; acc1 *= sc; dsum *= sc; m = cm;
      }
      const float w = (p < end) ? __expf(e - m) : 0.f;
      dsum += w;
      const int cnt = min(64, end - base);
      #pragma unroll 8
      for (int k=0; k<cnt; k++){
        const int   sk = __builtin_amdgcn_readlane(s, k);
        const float wk = __uint_as_float((unsigned)__builtin_amdgcn_readlane((int)__float_as_uint(w), k));
        if (F == 128){
          const unsigned hv = *(const unsigned*)(h + (size_t)sk*128 + 2*lane);
          union{unsigned u; float f;} lo, hi;
          lo.u = hv << 16; hi.u = hv & 0xffff0000u;
          acc0 += wk*lo.f; acc1 += wk*hi.f;
        } else {
          acc0 += wk * (float)h[(size_t)sk*F + lane];
        }
      }
    }
    #pragma unroll
    for (int o=32; o; o>>=1) dsum += __shfl_xor(dsum, o);
    const float wself = __expf(e_self - m);
    dsum += wself;
    const float inv = 1.f / dsum;
    if (F == 128){
      const unsigned hv = *(const unsigned*)(h + (size_t)i*128 + 2*lane);
      union{unsigned u; float f;} lo, hi;
      lo.u = hv << 16; hi.u = hv & 0xffff0000u;
      float o0 = (acc0 + wself*lo.f)*inv + bias[2*lane];
      float o1 = (acc1 + wself*hi.f)*inv + bias[2*lane+1];
      if (ACT){ o0 = lrelu(o0, 0.1f); o1 = lrelu(o1, 0.1f); }
      y[(size_t)i*128 + 2*lane]     = (__bf16)o0;
      y[(size_t)i*128 + 2*lane + 1] = (__bf16)o1;
    } else {
      float o0 = (acc0 + wself*(float)h[(size_t)i*F + lane])*inv + bias[lane];
      if (ACT) o0 = lrelu(o0, 0.1f);
      y[(size_t)i*F + lane] = (__bf16)o0;
    }
  }
}

extern "C" void kernel_launch(void* const* d_in, const int* in_sizes, int n_in,
                              void* d_out, int out_size, void* d_ws, size_t ws_size,
                              hipStream_t stream){
  const float* x   = (const float*)d_in[0];
  const int*   ei  = (const int*)d_in[1];
  const float* W1  = (const float*)d_in[2];
  const float* a1s = (const float*)d_in[3];
  const float* a1d = (const float*)d_in[4];
  const float* b1  = (const float*)d_in[5];
  const float* W2  = (const float*)d_in[6];
  const float* a2s = (const float*)d_in[7];
  const float* a2d = (const float*)d_in[8];
  const float* b2  = (const float*)d_in[9];
  const float* W3  = (const float*)d_in[10];
  const float* a3s = (const float*)d_in[11];
  const float* a3d = (const float*)d_in[12];
  const float* b3  = (const float*)d_in[13];
  const float* S   = (const float*)d_in[14];
  float* out = (float*)d_out;            // fp32 output

  const int N = in_sizes[0] / 128;   // 50000
  const int E = in_sizes[1] / 2;     // 800000

  char* w = (char*)d_ws;
  size_t o = 0;
  auto alloc = [&](size_t bytes)->void*{
    void* p = w + o; o += bytes; o = (o + 255) & ~(size_t)255; return p;
  };
  int*    off    = (int*)   alloc((size_t)(N+1)*4);
  int*    cursor = (int*)   alloc((size_t)N*4);
  int*    bsum   = (int*)   alloc(64*4);
  int*    flag   = (int*)   alloc(4);
  int*    csr    = (int*)   alloc((size_t)E*4);
  float*  as_    = (float*) alloc((size_t)N*4);
  float*  ad_    = (float*) alloc((size_t)N*4);
  __bf16* hb     = (__bf16*)alloc((size_t)N*128*2);
  __bf16* yb     = (__bf16*)alloc((size_t)N*128*2);
  __bf16* W1T    = (__bf16*)alloc(128*128*2);
  __bf16* W2T    = (__bf16*)alloc(128*128*2);
  __bf16* W3T    = (__bf16*)alloc(64*128*2);
  __bf16* Sb     = (__bf16*)alloc(512*64*2);
  (void)ws_size; (void)n_in; (void)out_size;

  // weight prep + flag detect + cursor zero (1 launch; 73728 threads >= N)
  prep_k<<<288, 256, 0, stream>>>(W1, W2, W3, S, ei, W1T, W2T, W3T, Sb, flag, cursor, N);

  // CSR build (shared by all 3 layers)
  hist_k<<<(E+255)/256, 256, 0, stream>>>(ei, flag, E, cursor);
  int nb = (N + 1023) / 1024;
  scan1_k<<<nb, 1024, 0, stream>>>(cursor, off, bsum, N);
  scan3_k<<<nb, 1024, 0, stream>>>(off, bsum, cursor, N, E);
  scatter_k<<<(E+255)/256, 256, 0, stream>>>(ei, flag, E, cursor, csr);

  const int gx = (N + 63) / 64;
  // Layer 1 (A = fp32 x)
  gemm_k<128,true,true,true><<<dim3(gx,1), 256, 0, stream>>>(
      nullptr, x, W1T, nullptr, hb, a1s, a1d, as_, ad_, N, 128);
  aggregate_k<128,1><<<2048, 256, 0, stream>>>(hb, as_, ad_, off, csr, b1, yb, N);
  // Layer 2
  gemm_k<128,false,true,true><<<dim3(gx,1), 256, 0, stream>>>(
      yb, nullptr, W2T, nullptr, hb, a2s, a2d, as_, ad_, N, 128);
  aggregate_k<128,1><<<2048, 256, 0, stream>>>(hb, as_, ad_, off, csr, b2, yb, N);
  // Layer 3 (Ntot = 64)
  gemm_k<128,false,true,true><<<dim3(gx,1), 256, 0, stream>>>(
      yb, nullptr, W3T, nullptr, hb, a3s, a3d, as_, ad_, N, 64);
  aggregate_k<64,0><<<2048, 256, 0, stream>>>(hb, as_, ad_, off, csr, b3, yb, N);
  // Final projection: out[N,512] = y[N,64] @ S^T  (BT = S itself, cast to bf16)
  gemm_k<64,false,false,false><<<dim3(gx,4), 256, 0, stream>>>(
      yb, nullptr, Sb, out, nullptr, nullptr, nullptr, nullptr, nullptr, N, 512);
}

// Round 2
// 398.080 us; speedup vs baseline: 1.1263x; 1.1263x over previous
//
#include <hip/hip_runtime.h>

typedef __bf16 bf16x8 __attribute__((ext_vector_type(8)));
typedef float  f32x4  __attribute__((ext_vector_type(4)));

#define CSR_CAP 80   // padded-CSR slots per node; E/N = 16 avg (Poisson), P(deg>80) ~ 0

__device__ __forceinline__ float lrelu(float x, float s){ return x > 0.f ? x : s*x; }

// ---------------- prep: weights fp32 -> bf16 TRANSPOSED, S cast, flag detect, cnt/ovfn zero ----
__global__ void prep_k(const float* __restrict__ W1, const float* __restrict__ W2,
                       const float* __restrict__ W3, const float* __restrict__ S,
                       const int* __restrict__ ei,
                       __bf16* __restrict__ W1T, __bf16* __restrict__ W2T,
                       __bf16* __restrict__ W3T, __bf16* __restrict__ Sb,
                       int* __restrict__ flag, int* __restrict__ cnt,
                       int* __restrict__ ovfn, int N){
  int t = blockIdx.x*256 + threadIdx.x;
  if (t < N) cnt[t] = 0;
  if (t == 0){
    int is64 = 1;
    for (int k=1; k<64; k+=2) if (ei[k] != 0){ is64 = 0; break; }
    *flag = is64;
  }
  if (t == 1) *ovfn = 0;
  if (t < 16384){ int k = t>>7, n = t&127; W1T[n*128 + k] = (__bf16)W1[t]; }
  else if (t < 32768){ int i = t-16384; int k = i>>7, n = i&127; W2T[n*128 + k] = (__bf16)W2[i]; }
  else if (t < 40960){ int i = t-32768; int k = i>>6, n = i&63;  W3T[n*128 + k] = (__bf16)W3[i]; }
  else if (t < 73728){ int i = t-40960; Sb[i] = (__bf16)S[i]; }
}

// ---------------- GEMM body (shared by standalone + fused kernels) ----------------
// C[M,Ntot] = A[M,K] @ B; B pre-transposed as BTg[Ntot][K] -> staging is straight b128 copies.
// A frag: A[m=lane&15][k=(lane>>4)*8+j]; B frag: BT[n=lane&15][k]; C/D: col=lane&15, row=(lane>>4)*4+reg.
template<int K, bool AF32, bool ALPH, bool OUTBF>
__device__ __forceinline__ void gemm_body(int bx, int by,
        const __bf16* __restrict__ A, const float* __restrict__ Af,
        const __bf16* __restrict__ BTg,
        float* __restrict__ Cf, __bf16* __restrict__ Cb,
        const float* __restrict__ avs, const float* __restrict__ avd,
        float* __restrict__ as_, float* __restrict__ ad_,
        int M, int Ntot){
  constexpr int KP = K + 8;                    // rows stay 16B-aligned, bank-alias-free
  constexpr int KV = K / 8;                    // bf16x8 chunks per row
  __shared__ __align__(16) __bf16 BT[128*KP];  // BT[n][k]
  const int n0 = by * 128;
  const int BN = min(128, Ntot - n0);
  const int tid = threadIdx.x;
  for (int idx = tid; idx < BN*KV; idx += 256){
    int nn = idx / KV, k8 = idx - nn*KV;       // KV power of 2 -> shifts
    *(bf16x8*)&BT[nn*KP + k8*8] = *(const bf16x8*)(BTg + (size_t)(n0+nn)*K + k8*8);
  }
  __syncthreads();
  const int lane = tid & 63, wave = tid >> 6;
  const int row0 = (bx*4 + wave) * 16;
  if (row0 >= M) return;
  const int m = lane & 15, kq = lane >> 4;
  bf16x8 af[K/32];
  if (AF32){
    const float* Ap = Af + (size_t)(row0 + m)*K + kq*8;
    #pragma unroll
    for (int ks=0; ks<K/32; ks++){
      f32x4 lo = *(const f32x4*)(Ap + ks*32);
      f32x4 hi = *(const f32x4*)(Ap + ks*32 + 4);
      bf16x8 v;
      #pragma unroll
      for (int j=0; j<4; j++){ v[j] = (__bf16)lo[j]; v[4+j] = (__bf16)hi[j]; }
      af[ks] = v;
    }
  } else {
    const __bf16* Ap = A + (size_t)(row0 + m)*K + kq*8;
    #pragma unroll
    for (int ks=0; ks<K/32; ks++) af[ks] = *(const bf16x8*)(Ap + ks*32);
  }
  float ps[4] = {0,0,0,0}, pd[4] = {0,0,0,0};
  const int ntc = BN >> 4;
  for (int nt=0; nt<ntc; nt++){
    f32x4 acc = {0.f, 0.f, 0.f, 0.f};
    const __bf16* Bp = &BT[(nt*16 + m)*KP + kq*8];
    #pragma unroll
    for (int ks=0; ks<K/32; ks++){
      bf16x8 bf = *(const bf16x8*)(Bp + ks*32);
      acc = __builtin_amdgcn_mfma_f32_16x16x32_bf16(af[ks], bf, acc, 0, 0, 0);
    }
    if (ALPH){
      float vs = avs[n0 + nt*16 + m], vd = avd[n0 + nt*16 + m];
      #pragma unroll
      for (int r=0; r<4; r++){ ps[r] += acc[r]*vs; pd[r] += acc[r]*vd; }
    }
    size_t cb = (size_t)(row0 + kq*4)*Ntot + (n0 + nt*16 + m);
    #pragma unroll
    for (int r=0; r<4; r++){
      if (OUTBF) Cb[cb + (size_t)r*Ntot] = (__bf16)acc[r];
      else       Cf[cb + (size_t)r*Ntot] = acc[r];
    }
  }
  if (ALPH){
    #pragma unroll
    for (int o=1; o<16; o<<=1){
      #pragma unroll
      for (int r=0; r<4; r++){ ps[r] += __shfl_xor(ps[r], o); pd[r] += __shfl_xor(pd[r], o); }
    }
    if (m == 0){
      #pragma unroll
      for (int r=0; r<4; r++){
        as_[row0 + kq*4 + r] = ps[r];
        ad_[row0 + kq*4 + r] = pd[r];
      }
    }
  }
}

template<int K, bool AF32, bool ALPH, bool OUTBF>
__global__ __launch_bounds__(256) void gemm_k(const __bf16* __restrict__ A,
        const float* __restrict__ Af, const __bf16* __restrict__ BTg,
        float* __restrict__ Cf, __bf16* __restrict__ Cb,
        const float* __restrict__ avs, const float* __restrict__ avd,
        float* __restrict__ as_, float* __restrict__ ad_,
        int M, int Ntot){
  gemm_body<K,AF32,ALPH,OUTBF>(blockIdx.x, blockIdx.y, A, Af, BTg, Cf, Cb,
                               avs, avd, as_, ad_, M, Ntot);
}

// ---------------- fused: layer-1 GEMM (blocks < gx)  ||  padded-CSR scatter (blocks >= gx) ----
// The two halves are independent (both only need prep_k): MFMA-bound GEMM waves hide the
// latency-bound random-atomic scatter. pos = atomicAdd(cnt[d]); slot d*CAP+pos; spill -> ovf.
__global__ __launch_bounds__(256) void gemm1_scatter_k(
        const float* __restrict__ x, const __bf16* __restrict__ W1T,
        __bf16* __restrict__ hb, const float* __restrict__ a1s,
        const float* __restrict__ a1d, float* __restrict__ as_,
        float* __restrict__ ad_, int M,
        const int* __restrict__ ei, const int* __restrict__ flag, int E,
        int* __restrict__ cnt, int* __restrict__ csr,
        int* __restrict__ ovfn, int* __restrict__ ovf, int gx){
  if ((int)blockIdx.x < gx){
    gemm_body<128,true,true,true>(blockIdx.x, 0, nullptr, x, W1T, nullptr, hb,
                                  a1s, a1d, as_, ad_, M, 128);
    return;
  }
  const int f = *flag;
  const long T = (long)(gridDim.x - gx) * 256;
  const long t0 = ((long)blockIdx.x - gx)*256 + threadIdx.x;
  for (long t = t0; t < E; t += T){
    int s = ei[f ? 2L*t           : t];
    int d = ei[f ? 2L*((long)E+t) : ((long)E+t)];
    int pos = atomicAdd(&cnt[d], 1);
    if (pos < CSR_CAP) csr[(long)d*CSR_CAP + pos] = s;
    else { int op = atomicAdd(ovfn, 1); ovf[2*op] = d; ovf[2*op+1] = s; }
  }
}

// ---------------- per-dst-node softmax aggregation: single-pass online softmax ----------------
// One wave per node (persistent). Padded CSR: row i = csr[i*CAP .. i*CAP+min(cnt,CAP)),
// contiguous + coalesced. w/s broadcast via readlane (SGPR base for the h-row gather).
template<int F, int ACT>
__global__ __launch_bounds__(256) void aggregate_k(const __bf16* __restrict__ h,
        const float* __restrict__ as, const float* __restrict__ ad,
        const int* __restrict__ cnt, const int* __restrict__ csr,
        const int* __restrict__ ovfn, const int* __restrict__ ovf,
        const float* __restrict__ bias, __bf16* __restrict__ y, int N){
  const int lane = threadIdx.x & 63;
  const int wid  = (blockIdx.x*256 + threadIdx.x) >> 6;
  const int nw   = gridDim.x * 4;
  const int nov  = *ovfn;                      // 0 in practice: one scalar load
  for (int i = wid; i < N; i += nw){
    const int deg = min(cnt[i], CSR_CAP);
    const long b0 = (long)i*CSR_CAP;
    const float adi = ad[i];
    const float e_self = lrelu(as[i] + adi, 0.2f);
    float m = e_self, dsum = 0.f, acc0 = 0.f, acc1 = 0.f;
    for (int base = 0; base < deg; base += 64){
      const int p = base + lane;
      int s = 0; float e = -1e30f;
      if (p < deg){ s = csr[b0 + p]; e = lrelu(as[s] + adi, 0.2f); }
      float cm = e;
      #pragma unroll
      for (int o=32; o; o>>=1) cm = fmaxf(cm, __shfl_xor(cm, o));
      if (cm > m){                             // wave-uniform
        const float sc = __expf(m - cm);
        acc0 *= sc; acc1 *= sc; dsum *= sc; m = cm;
      }
      const float w = (p < deg) ? __expf(e - m) : 0.f;
      dsum += w;
      const int c = min(64, deg - base);
      #pragma unroll 8
      for (int k=0; k<c; k++){
        const int   sk = __builtin_amdgcn_readlane(s, k);
        const float wk = __uint_as_float((unsigned)__builtin_amdgcn_readlane((int)__float_as_uint(w), k));
        if (F == 128){
          const unsigned hv = *(const unsigned*)(h + (size_t)sk*128 + 2*lane);
          union{unsigned u; float f;} lo, hi;
          lo.u = hv << 16; hi.u = hv & 0xffff0000u;
          acc0 += wk*lo.f; acc1 += wk*hi.f;
        } else {
          acc0 += wk * (float)h[(size_t)sk*F + lane];
        }
      }
    }
    if (nov > 0){                              // spill path: correctness only, never hot
      for (int base = 0; base < nov; base += 64){
        const int p = base + lane;
        int s = 0; float e = -1e30f;
        if (p < nov && ovf[2*p] == i){ s = ovf[2*p+1]; e = lrelu(as[s] + adi, 0.2f); }
        float cm = e;
        #pragma unroll
        for (int o=32; o; o>>=1) cm = fmaxf(cm, __shfl_xor(cm, o));
        if (cm > m){
          const float sc = __expf(m - cm);
          acc0 *= sc; acc1 *= sc; dsum *= sc; m = cm;
        }
        const float w = (e > -1e29f) ? __expf(e - m) : 0.f;
        dsum += w;
        const int c = min(64, nov - base);
        for (int k=0; k<c; k++){
          const int   sk = __builtin_amdgcn_readlane(s, k);
          const float wk = __uint_as_float((unsigned)__builtin_amdgcn_readlane((int)__float_as_uint(w), k));
          if (wk == 0.f) continue;
          if (F == 128){
            const unsigned hv = *(const unsigned*)(h + (size_t)sk*128 + 2*lane);
            union{unsigned u; float f;} lo, hi;
            lo.u = hv << 16; hi.u = hv & 0xffff0000u;
            acc0 += wk*lo.f; acc1 += wk*hi.f;
          } else {
            acc0 += wk * (float)h[(size_t)sk*F + lane];
          }
        }
      }
    }
    #pragma unroll
    for (int o=32; o; o>>=1) dsum += __shfl_xor(dsum, o);
    const float wself = __expf(e_self - m);
    dsum += wself;
    const float inv = 1.f / dsum;
    if (F == 128){
      const unsigned hv = *(const unsigned*)(h + (size_t)i*128 + 2*lane);
      union{unsigned u; float f;} lo, hi;
      lo.u = hv << 16; hi.u = hv & 0xffff0000u;
      float o0 = (acc0 + wself*lo.f)*inv + bias[2*lane];
      float o1 = (acc1 + wself*hi.f)*inv + bias[2*lane+1];
      if (ACT){ o0 = lrelu(o0, 0.1f); o1 = lrelu(o1, 0.1f); }
      y[(size_t)i*128 + 2*lane]     = (__bf16)o0;
      y[(size_t)i*128 + 2*lane + 1] = (__bf16)o1;
    } else {
      float o0 = (acc0 + wself*(float)h[(size_t)i*F + lane])*inv + bias[lane];
      if (ACT) o0 = lrelu(o0, 0.1f);
      y[(size_t)i*F + lane] = (__bf16)o0;
    }
  }
}

extern "C" void kernel_launch(void* const* d_in, const int* in_sizes, int n_in,
                              void* d_out, int out_size, void* d_ws, size_t ws_size,
                              hipStream_t stream){
  const float* x   = (const float*)d_in[0];
  const int*   ei  = (const int*)d_in[1];
  const float* W1  = (const float*)d_in[2];
  const float* a1s = (const float*)d_in[3];
  const float* a1d = (const float*)d_in[4];
  const float* b1  = (const float*)d_in[5];
  const float* W2  = (const float*)d_in[6];
  const float* a2s = (const float*)d_in[7];
  const float* a2d = (const float*)d_in[8];
  const float* b2  = (const float*)d_in[9];
  const float* W3  = (const float*)d_in[10];
  const float* a3s = (const float*)d_in[11];
  const float* a3d = (const float*)d_in[12];
  const float* b3  = (const float*)d_in[13];
  const float* S   = (const float*)d_in[14];
  float* out = (float*)d_out;            // fp32 output

  const int N = in_sizes[0] / 128;   // 50000
  const int E = in_sizes[1] / 2;     // 800000

  char* w = (char*)d_ws;
  size_t o = 0;
  auto alloc = [&](size_t bytes)->void*{
    void* p = w + o; o += bytes; o = (o + 255) & ~(size_t)255; return p;
  };
  int*    cnt    = (int*)   alloc((size_t)N*4);
  int*    csr    = (int*)   alloc((size_t)N*CSR_CAP*4);
  int*    ovfn   = (int*)   alloc(4);
  int*    ovf    = (int*)   alloc(65536);
  int*    flag   = (int*)   alloc(4);
  float*  as_    = (float*) alloc((size_t)N*4);
  float*  ad_    = (float*) alloc((size_t)N*4);
  __bf16* hb     = (__bf16*)alloc((size_t)N*128*2);
  __bf16* yb     = (__bf16*)alloc((size_t)N*128*2);
  __bf16* W1T    = (__bf16*)alloc(128*128*2);
  __bf16* W2T    = (__bf16*)alloc(128*128*2);
  __bf16* W3T    = (__bf16*)alloc(64*128*2);
  __bf16* Sb     = (__bf16*)alloc(512*64*2);
  (void)ws_size; (void)n_in; (void)out_size;

  const int gx = (N + 63) / 64;      // 782

  // K1: weight prep + flag detect + cnt/ovfn zero
  prep_k<<<288, 256, 0, stream>>>(W1, W2, W3, S, ei, W1T, W2T, W3T, Sb, flag, cnt, ovfn, N);
  // K2: layer-1 GEMM || padded-CSR scatter (independent halves, overlapped)
  gemm1_scatter_k<<<gx + 1024, 256, 0, stream>>>(
      x, W1T, hb, a1s, a1d, as_, ad_, N, ei, flag, E, cnt, csr, ovfn, ovf, gx);
  aggregate_k<128,1><<<2048, 256, 0, stream>>>(hb, as_, ad_, cnt, csr, ovfn, ovf, b1, yb, N);
  // Layer 2
  gemm_k<128,false,true,true><<<dim3(gx,1), 256, 0, stream>>>(
      yb, nullptr, W2T, nullptr, hb, a2s, a2d, as_, ad_, N, 128);
  aggregate_k<128,1><<<2048, 256, 0, stream>>>(hb, as_, ad_, cnt, csr, ovfn, ovf, b2, yb, N);
  // Layer 3 (Ntot = 64)
  gemm_k<128,false,true,true><<<dim3(gx,1), 256, 0, stream>>>(
      yb, nullptr, W3T, nullptr, hb, a3s, a3d, as_, ad_, N, 64);
  aggregate_k<64,0><<<2048, 256, 0, stream>>>(hb, as_, ad_, cnt, csr, ovfn, ovf, b3, yb, N);
  // Final projection: out[N,512] = y[N,64] @ S^T  (BT = S itself, cast to bf16)
  gemm_k<64,false,false,false><<<dim3(gx,4), 256, 0, stream>>>(
      yb, nullptr, Sb, out, nullptr, nullptr, nullptr, nullptr, nullptr, N, 512);
}